// Round 5
// baseline (329.860 us; speedup 1.0000x reference)
//
#include <hip/hip_runtime.h>
#include <hip/hip_bf16.h>

// B=8192, T=512, IN=1, H=20, OUT=1
#define B_TOTAL 8192
#define T_LEN   512
#define H       20
#define NBW     3      // real batches per wave (3*20=60 lanes; lanes 60-63 dummies -> row 3)
#define XSTR    520    // xs row stride (520%32==8 -> conflict-free)

__device__ __forceinline__ float fast_tanh(float x) {
    float e = __expf(x + x);
    return 1.0f - 2.0f * __builtin_amdgcn_rcpf(e + 1.0f);
}

// Load 20 floats (5x float4) from LDS into named regs.
#define RD5(dst, base) \
    float4 dst##a = ((const float4*)(base))[0]; \
    float4 dst##b = ((const float4*)(base))[1]; \
    float4 dst##c = ((const float4*)(base))[2]; \
    float4 dst##d = ((const float4*)(base))[3]; \
    float4 dst##e = ((const float4*)(base))[4];

// acc += h . wt ; wt is float4[5] in registers (static indices), 2 acc chains.
// NOTE: macro param must NOT be named 'w' (collides with .w field accessor).
#define DOT20(accA, accB, hv, wt) \
    accA = fmaf(hv##a.x, wt[0].x, accA); accB = fmaf(hv##a.y, wt[0].y, accB); \
    accA = fmaf(hv##a.z, wt[0].z, accA); accB = fmaf(hv##a.w, wt[0].w, accB); \
    accA = fmaf(hv##b.x, wt[1].x, accA); accB = fmaf(hv##b.y, wt[1].y, accB); \
    accA = fmaf(hv##b.z, wt[1].z, accA); accB = fmaf(hv##b.w, wt[1].w, accB); \
    accA = fmaf(hv##c.x, wt[2].x, accA); accB = fmaf(hv##c.y, wt[2].y, accB); \
    accA = fmaf(hv##c.z, wt[2].z, accA); accB = fmaf(hv##c.w, wt[2].w, accB); \
    accA = fmaf(hv##d.x, wt[3].x, accA); accB = fmaf(hv##d.y, wt[3].y, accB); \
    accA = fmaf(hv##d.z, wt[3].z, accA); accB = fmaf(hv##d.w, wt[3].w, accB); \
    accA = fmaf(hv##e.x, wt[4].x, accA); accB = fmaf(hv##e.y, wt[4].y, accB); \
    accA = fmaf(hv##e.z, wt[4].z, accA); accB = fmaf(hv##e.w, wt[4].w, accB);

// One diagonal-pipeline tick: produce h0(s) [DO0], h1(s-1) [DO1], h2(s-2) [DO2].
// Single wave => DS in-order, reads precede writes, no barriers.
#define TICK(sidx, DO0, DO1, DO2) { \
    float t0 = 0.f, t1 = 0.f, t2 = 0.f; \
    if (DO0 || DO1) { \
        RD5(h0v, &h0s[bb][0]) \
        if (DO0) { \
            float a0A = fmaf(xs[bb][(sidx)], wih0j, bias0), a0B = 0.f; \
            DOT20(a0A, a0B, h0v, whh0r) \
            t0 = fast_tanh(a0A + a0B); \
        } \
        if (DO1) { \
            float a1A = bias1, a1B = 0.f; \
            DOT20(a1A, a1B, h0v, wih1r) \
            RD5(h1vA, &h1s[bb][0]) \
            float a1C = 0.f, a1D = 0.f; \
            DOT20(a1C, a1D, h1vA, whh1r) \
            t1 = fast_tanh(a1A + a1B + a1C + a1D); \
            if (DO2) { \
                float a2A = bias2, a2B = 0.f; \
                DOT20(a2A, a2B, h1vA, wih2r) \
                RD5(h2v, &h2s[bb][0]) \
                float a2C = 0.f, a2D = 0.f; \
                DOT20(a2C, a2D, h2v, whh2r) \
                t2 = fast_tanh(a2A + a2B + a2C + a2D); \
            } \
        } else if (DO2) { \
            RD5(h1vB, &h1s[bb][0]) \
            float a2A = bias2, a2B = 0.f; \
            DOT20(a2A, a2B, h1vB, wih2r) \
            RD5(h2v, &h2s[bb][0]) \
            float a2C = 0.f, a2D = 0.f; \
            DOT20(a2C, a2D, h2v, whh2r) \
            t2 = fast_tanh(a2A + a2B + a2C + a2D); \
        } \
    } else if (DO2) { \
        RD5(h1vC, &h1s[bb][0]) \
        float a2A = bias2, a2B = 0.f; \
        DOT20(a2A, a2B, h1vC, wih2r) \
        RD5(h2v, &h2s[bb][0]) \
        float a2C = 0.f, a2D = 0.f; \
        DOT20(a2C, a2D, h2v, whh2r) \
        t2 = fast_tanh(a2A + a2B + a2C + a2D); \
    } \
    if (DO0) h0s[bb][j] = t0; \
    if (DO1) h1s[bb][j] = t1; \
    if (DO2) h2s[bb][j] = t2; \
}

__global__ __launch_bounds__(64, 3) void rnn_wave(
    const float* __restrict__ x,
    const float* __restrict__ w_ih0, const float* __restrict__ w_hh0,
    const float* __restrict__ b_ih0, const float* __restrict__ b_hh0,
    const float* __restrict__ w_ih1, const float* __restrict__ w_hh1,
    const float* __restrict__ b_ih1, const float* __restrict__ b_hh1,
    const float* __restrict__ w_ih2, const float* __restrict__ w_hh2,
    const float* __restrict__ b_ih2, const float* __restrict__ b_hh2,
    const float* __restrict__ fc_w,  const float* __restrict__ fc_b,
    float* __restrict__ out)
{
    __shared__ __align__(16) float xs[4][XSTR];
    __shared__ __align__(16) float h0s[4][H];
    __shared__ __align__(16) float h1s[4][H];
    __shared__ __align__(16) float h2s[4][H];

    const int lane = threadIdx.x;      // block == one wave
    const int bb   = lane / H;         // 0..3 (3 = dummy lanes)
    const int j    = lane - bb * H;    // 0..19
    const int gb   = blockIdx.x * NBW + bb;

    // ---- one-time: stage x rows (coalesced float4), zero h state ----
    {
        const int gb0 = blockIdx.x * NBW;
        #pragma unroll
        for (int it = 0; it < 6; ++it) {
            int fidx = (it * 64 + lane) * 4;
            int row  = fidx >> 9;
            int col  = fidx & 511;
            int grow = gb0 + row;
            if (grow > B_TOTAL - 1) grow = B_TOTAL - 1;
            float4 v = *(const float4*)(x + (size_t)grow * T_LEN + col);
            *(float4*)&xs[row][col] = v;
        }
        for (int i = lane; i < 4 * H; i += 64) {
            (&h0s[0][0])[i] = 0.f;
            (&h1s[0][0])[i] = 0.f;
            (&h2s[0][0])[i] = 0.f;
        }
        for (int i = lane; i < XSTR; i += 64) xs[3][i] = 0.f;
    }

    // ---- per-lane weight rows (row j), float4-vectorized, PINNED in VGPRs ----
    float4 whh0r[5], wih1r[5], whh1r[5], wih2r[5], whh2r[5];
    {
        const float4* p0 = (const float4*)(w_hh0 + j * H);
        const float4* p1 = (const float4*)(w_ih1 + j * H);
        const float4* p2 = (const float4*)(w_hh1 + j * H);
        const float4* p3 = (const float4*)(w_ih2 + j * H);
        const float4* p4 = (const float4*)(w_hh2 + j * H);
        #pragma unroll
        for (int q = 0; q < 5; ++q) {
            whh0r[q] = p0[q]; wih1r[q] = p1[q]; whh1r[q] = p2[q];
            wih2r[q] = p3[q]; whh2r[q] = p4[q];
        }
        #pragma unroll
        for (int q = 0; q < 5; ++q) {
            asm volatile("" : "+v"(whh0r[q].x), "+v"(whh0r[q].y), "+v"(whh0r[q].z), "+v"(whh0r[q].w));
            asm volatile("" : "+v"(wih1r[q].x), "+v"(wih1r[q].y), "+v"(wih1r[q].z), "+v"(wih1r[q].w));
            asm volatile("" : "+v"(whh1r[q].x), "+v"(whh1r[q].y), "+v"(whh1r[q].z), "+v"(whh1r[q].w));
            asm volatile("" : "+v"(wih2r[q].x), "+v"(wih2r[q].y), "+v"(wih2r[q].z), "+v"(wih2r[q].w));
            asm volatile("" : "+v"(whh2r[q].x), "+v"(whh2r[q].y), "+v"(whh2r[q].z), "+v"(whh2r[q].w));
        }
    }
    const float wih0j = w_ih0[j];
    const float bias0 = b_ih0[j] + b_hh0[j];
    const float bias1 = b_ih1[j] + b_hh1[j];
    const float bias2 = b_ih2[j] + b_hh2[j];

    // ---- diagonal pipeline, wave-synchronous ----
    TICK(0, 1, 0, 0)
    TICK(1, 1, 1, 0)
    for (int s = 2; s < T_LEN; ++s) {
        TICK(s, 1, 1, 1)
    }
    TICK(512, 0, 1, 1)   // h1(511), h2(510)
    TICK(513, 0, 0, 1)   // h2(511)

    // ---- FC epilogue ----
    if (j == 0 && bb < NBW && gb < B_TOTAL) {
        float acc = fc_b[0];
        #pragma unroll
        for (int k = 0; k < H; ++k)
            acc = fmaf(h2s[bb][k], fc_w[k], acc);
        out[gb] = acc;
    }
}

extern "C" void kernel_launch(void* const* d_in, const int* in_sizes, int n_in,
                              void* d_out, int out_size, void* d_ws, size_t ws_size,
                              hipStream_t stream) {
    const float* x     = (const float*)d_in[0];
    const float* w_ih0 = (const float*)d_in[1];
    const float* w_hh0 = (const float*)d_in[2];
    const float* b_ih0 = (const float*)d_in[3];
    const float* b_hh0 = (const float*)d_in[4];
    const float* w_ih1 = (const float*)d_in[5];
    const float* w_hh1 = (const float*)d_in[6];
    const float* b_ih1 = (const float*)d_in[7];
    const float* b_hh1 = (const float*)d_in[8];
    const float* w_ih2 = (const float*)d_in[9];
    const float* w_hh2 = (const float*)d_in[10];
    const float* b_ih2 = (const float*)d_in[11];
    const float* b_hh2 = (const float*)d_in[12];
    const float* fc_w  = (const float*)d_in[13];
    const float* fc_b  = (const float*)d_in[14];
    float* out = (float*)d_out;

    const int nblocks = (B_TOTAL + NBW - 1) / NBW;   // 2731
    rnn_wave<<<nblocks, 64, 0, stream>>>(
        x, w_ih0, w_hh0, b_ih0, b_hh0,
        w_ih1, w_hh1, b_ih1, b_hh1,
        w_ih2, w_hh2, b_ih2, b_hh2,
        fc_w, fc_b, out);
}

// Round 6
// 262.154 us; speedup vs baseline: 1.2583x; 1.2583x over previous
//
#include <hip/hip_runtime.h>
#include <hip/hip_bf16.h>
#include <hip/hip_fp16.h>

// B=8192, T=512, IN=1, H=20, OUT=1
#define B_TOTAL 8192
#define T_LEN   512
#define H       20
#define NBW     3      // batches per wave (3*20=60 lanes; 60-63 dummies -> row 3)
#define XSTR    520    // xs row stride in floats (520%32==8 -> conflict-free)
#define HROWU   12     // h row stride in uints (12*4=48B; 10 used = 20 halves)

typedef _Float16 half2v __attribute__((ext_vector_type(2)));

#if __has_builtin(__builtin_amdgcn_fdot2)
#define FDOT2(a, b, c) __builtin_amdgcn_fdot2((a), (b), (c), false)
#else
#define FDOT2(a, b, c) fmaf((float)(a).x, (float)(b).x, fmaf((float)(a).y, (float)(b).y, (c)))
#endif

__device__ __forceinline__ float fast_tanh(float x) {
    float e = __expf(x + x);
    return 1.0f - 2.0f * __builtin_amdgcn_rcpf(e + 1.0f);
}

__device__ __forceinline__ half2v h2v(unsigned int u) {
    return __builtin_bit_cast(half2v, u);
}

// Load 20 halves (10 packed pairs) from LDS: b128 + b128 + b64.
#define RDH(dst, base) \
    uint4 dst##A = ((const uint4*)(base))[0]; \
    uint4 dst##B = ((const uint4*)(base))[1]; \
    uint2 dst##C = *(const uint2*)(((const unsigned int*)(base)) + 8);

// acc0/acc1 += h . wt  (10 x v_dot2_f32_f16, 2 chains)
#define DOTH(acc0, acc1, hv, wt) \
    acc0 = FDOT2(h2v(hv##A.x), wt[0], acc0); acc1 = FDOT2(h2v(hv##A.y), wt[1], acc1); \
    acc0 = FDOT2(h2v(hv##A.z), wt[2], acc0); acc1 = FDOT2(h2v(hv##A.w), wt[3], acc1); \
    acc0 = FDOT2(h2v(hv##B.x), wt[4], acc0); acc1 = FDOT2(h2v(hv##B.y), wt[5], acc1); \
    acc0 = FDOT2(h2v(hv##B.z), wt[6], acc0); acc1 = FDOT2(h2v(hv##B.w), wt[7], acc1); \
    acc0 = FDOT2(h2v(hv##C.x), wt[8], acc0); acc1 = FDOT2(h2v(hv##C.y), wt[9], acc1);

// One diagonal-pipeline tick: h0(s) [DO0], h1(s-1) [DO1], h2(s-2) [DO2].
// Single wave => DS in-order; all reads precede writes in program order.
#define TICK(sidx, DO0, DO1, DO2) { \
    float t0 = 0.f, t1 = 0.f, t2 = 0.f; \
    if (DO0 || DO1) { \
        RDH(h0v, &h0s[bb][0]) \
        if (DO0) { \
            float a0 = fmaf(xs[bb][(sidx)], wih0j, bias0), a0b = 0.f; \
            DOTH(a0, a0b, h0v, whh0r) \
            t0 = fast_tanh(a0 + a0b); \
        } \
        if (DO1) { \
            float a1 = bias1, a1b = 0.f; \
            DOTH(a1, a1b, h0v, wih1r) \
            RDH(h1v, &h1s[bb][0]) \
            DOTH(a1, a1b, h1v, whh1r) \
            t1 = fast_tanh(a1 + a1b); \
            if (DO2) { \
                float a2 = bias2, a2b = 0.f; \
                DOTH(a2, a2b, h1v, wih2r) \
                RDH(h2v, &h2s[bb][0]) \
                DOTH(a2, a2b, h2v, whh2r) \
                t2 = fast_tanh(a2 + a2b); \
            } \
        } \
    } \
    if (!(DO1) && (DO2)) { \
        RDH(h1w, &h1s[bb][0]) \
        float a2 = bias2, a2b = 0.f; \
        DOTH(a2, a2b, h1w, wih2r) \
        RDH(h2w, &h2s[bb][0]) \
        DOTH(a2, a2b, h2w, whh2r) \
        t2 = fast_tanh(a2 + a2b); \
    } \
    if (DO0) ((__half*)&h0s[bb][0])[j] = (__half)t0; \
    if (DO1) ((__half*)&h1s[bb][0])[j] = (__half)t1; \
    if (DO2) ((__half*)&h2s[bb][0])[j] = (__half)t2; \
}

__global__ __attribute__((amdgpu_flat_work_group_size(64, 64), amdgpu_waves_per_eu(2, 3)))
void rnn_wave(
    const float* __restrict__ x,
    const float* __restrict__ w_ih0, const float* __restrict__ w_hh0,
    const float* __restrict__ b_ih0, const float* __restrict__ b_hh0,
    const float* __restrict__ w_ih1, const float* __restrict__ w_hh1,
    const float* __restrict__ b_ih1, const float* __restrict__ b_hh1,
    const float* __restrict__ w_ih2, const float* __restrict__ w_hh2,
    const float* __restrict__ b_ih2, const float* __restrict__ b_hh2,
    const float* __restrict__ fc_w,  const float* __restrict__ fc_b,
    float* __restrict__ out)
{
    __shared__ __align__(16) float        xs[4][XSTR];
    __shared__ __align__(16) unsigned int h0s[4][HROWU];   // 20 f16 + pad per row
    __shared__ __align__(16) unsigned int h1s[4][HROWU];
    __shared__ __align__(16) unsigned int h2s[4][HROWU];

    const int lane = threadIdx.x;      // block == one wave
    const int bb   = lane / H;         // 0..3 (3 = dummy lanes)
    const int j    = lane - bb * H;    // 0..19
    const int gb   = blockIdx.x * NBW + bb;

    // ---- one-time: stage x rows (coalesced float4), zero h state ----
    {
        const int gb0 = blockIdx.x * NBW;
        #pragma unroll
        for (int it = 0; it < 6; ++it) {
            int fidx = (it * 64 + lane) * 4;
            int row  = fidx >> 9;
            int col  = fidx & 511;
            int grow = gb0 + row;
            if (grow > B_TOTAL - 1) grow = B_TOTAL - 1;
            float4 v = *(const float4*)(x + (size_t)grow * T_LEN + col);
            *(float4*)&xs[row][col] = v;
        }
        for (int i = lane; i < 4 * HROWU; i += 64) {
            (&h0s[0][0])[i] = 0u;
            (&h1s[0][0])[i] = 0u;
            (&h2s[0][0])[i] = 0u;
        }
        for (int i = lane; i < XSTR; i += 64) xs[3][i] = 0.f;
    }

    // ---- per-lane weight rows (row j), converted to packed f16 pairs ----
    half2v whh0r[10], wih1r[10], whh1r[10], wih2r[10], whh2r[10];
    {
        const float* p0 = w_hh0 + j * H;
        const float* p1 = w_ih1 + j * H;
        const float* p2 = w_hh1 + j * H;
        const float* p3 = w_ih2 + j * H;
        const float* p4 = w_hh2 + j * H;
        #pragma unroll
        for (int q = 0; q < 10; ++q) {
            whh0r[q] = half2v{(_Float16)p0[2*q], (_Float16)p0[2*q+1]};
            wih1r[q] = half2v{(_Float16)p1[2*q], (_Float16)p1[2*q+1]};
            whh1r[q] = half2v{(_Float16)p2[2*q], (_Float16)p2[2*q+1]};
            wih2r[q] = half2v{(_Float16)p3[2*q], (_Float16)p3[2*q+1]};
            whh2r[q] = half2v{(_Float16)p4[2*q], (_Float16)p4[2*q+1]};
        }
    }
    const float wih0j = w_ih0[j];
    const float bias0 = b_ih0[j] + b_hh0[j];
    const float bias1 = b_ih1[j] + b_hh1[j];
    const float bias2 = b_ih2[j] + b_hh2[j];

    // ---- diagonal pipeline, wave-synchronous (no barriers) ----
    TICK(0, 1, 0, 0)
    TICK(1, 1, 1, 0)
    for (int s = 2; s < T_LEN; ++s) {
        TICK(s, 1, 1, 1)
    }
    TICK(512, 0, 1, 1)   // h1(511), h2(510)
    TICK(513, 0, 0, 1)   // h2(511)

    // ---- FC epilogue ----
    if (j == 0 && bb < NBW && gb < B_TOTAL) {
        float acc = fc_b[0];
        const __half* hp = (const __half*)&h2s[bb][0];
        #pragma unroll
        for (int k = 0; k < H; ++k)
            acc = fmaf((float)hp[k], fc_w[k], acc);
        out[gb] = acc;
    }
}

extern "C" void kernel_launch(void* const* d_in, const int* in_sizes, int n_in,
                              void* d_out, int out_size, void* d_ws, size_t ws_size,
                              hipStream_t stream) {
    const float* x     = (const float*)d_in[0];
    const float* w_ih0 = (const float*)d_in[1];
    const float* w_hh0 = (const float*)d_in[2];
    const float* b_ih0 = (const float*)d_in[3];
    const float* b_hh0 = (const float*)d_in[4];
    const float* w_ih1 = (const float*)d_in[5];
    const float* w_hh1 = (const float*)d_in[6];
    const float* b_ih1 = (const float*)d_in[7];
    const float* b_hh1 = (const float*)d_in[8];
    const float* w_ih2 = (const float*)d_in[9];
    const float* w_hh2 = (const float*)d_in[10];
    const float* b_ih2 = (const float*)d_in[11];
    const float* b_hh2 = (const float*)d_in[12];
    const float* fc_w  = (const float*)d_in[13];
    const float* fc_b  = (const float*)d_in[14];
    float* out = (float*)d_out;

    const int nblocks = (B_TOTAL + NBW - 1) / NBW;   // 2731
    rnn_wave<<<nblocks, 64, 0, stream>>>(
        x, w_ih0, w_hh0, b_ih0, b_hh0,
        w_ih1, w_hh1, b_ih1, b_hh1,
        w_ih2, w_hh2, b_ih2, b_hh2,
        fc_w, fc_b, out);
}